// Round 6
// baseline (288.052 us; speedup 1.0000x reference)
//
#include <hip/hip_runtime.h>

// Problem constants (match reference)
#define BATCH 8192
#define TSTEPS 200
#define FEAT 16
#define HID 32
#define GATES 128   // 4*HID, Keras order: i | f | cc | o
#define DOUT 60
#define ROWS 16     // batch rows per wave (one MFMA N-tile, transposed form)
#define HSTRIDE 40  // LDS h row stride in halves (final head pass only)

typedef __fp16 half2v __attribute__((ext_vector_type(2)));
typedef __fp16 half4v __attribute__((ext_vector_type(4)));
typedef __fp16 half8v __attribute__((ext_vector_type(8)));
typedef float  float4v __attribute__((ext_vector_type(4)));

__device__ __forceinline__ half2v pkrtz(float a, float b) {
    return __builtin_amdgcn_cvt_pkrtz(a, b);
}

__device__ __forceinline__ half4v pack4(float4 v) {
    half2v lo = pkrtz(v.x, v.y);
    half2v hi = pkrtz(v.z, v.w);
    half4v r;
    r[0] = lo[0]; r[1] = lo[1]; r[2] = hi[0]; r[3] = hi[1];
    return r;
}

// Gate-column permutation, K-SPLIT version. Tile tt = gate-type (tt>>1:
// i,f,cc,o) x half (tt&1). Column m -> unit 16*(tt&1) + m.
// Lane (g,n16) owns D rows m=4g+r, batch col n16, so the hf=0 epilogue emits
// h[units 4g+r][row n16] -- exactly the lane's K=4g+j B-frag for a 16x16x16
// MFMA over units 0..15 (U_lo) -- and hf=1 emits units 16+4g+r (U_hi frag).
// The K=32 h·U product becomes two chained K=16 MFMAs, so each half of the
// epilogue can feed the matrix pipe as soon as it finishes.
__device__ __forceinline__ int gcol(int tt, int m) {
    return 32 * (tt >> 1) + 16 * (tt & 1) + m;
}

union h4Un { half4v v; half2v h2[2]; };

// Half-epilogue for gate-half HF: consumes acc tiles {0,2,4,6}+HF, updates
// cst[HF], produces the 4-f16 h frag for that half. Trans-minimized
// (12 exp2 + 4 rcp per half), gates prescaled by -log2(e) in the weights.
template <int HF>
__device__ __forceinline__ void epi_half(
    const float4v (&acc)[8], float (&cst)[2][4], h4Un& hout)
{
    float ei[4], ef[4], eo[4];
    #pragma unroll
    for (int r = 0; r < 4; r++) {
        ei[r] = __builtin_amdgcn_exp2f(acc[0 + HF][r]);
        ef[r] = __builtin_amdgcn_exp2f(acc[2 + HF][r]);
        eo[r] = __builtin_amdgcn_exp2f(acc[6 + HF][r]);
    }
    float dd[4], num[4], dov[4];
    #pragma unroll
    for (int r = 0; r < 4; r++) {
        float di = 1.0f + ei[r];
        float df = 1.0f + ef[r];
        dov[r] = 1.0f + eo[r];
        float rc = fmaxf(acc[4 + HF][r], 0.0f);
        num[r] = fmaf(cst[HF][r], di, rc * df);
        dd[r]  = di * df;
    }
    #pragma unroll
    for (int p = 0; p < 2; p++) {
        const int r0 = 2 * p, r1 = 2 * p + 1;
        float Q  = __builtin_amdgcn_rcpf(dd[r0] * dd[r1]);
        float c0 = num[r0] * (dd[r1] * Q);
        float c1 = num[r1] * (dd[r0] * Q);
        cst[HF][r0] = c0;
        cst[HF][r1] = c1;
        float Qo = __builtin_amdgcn_rcpf(dov[r0] * dov[r1]);
        float h0 = fmaxf(c0, 0.0f) * (dov[r1] * Qo);
        float h1 = fmaxf(c1, 0.0f) * (dov[r0] * Qo);
        hout.h2[p] = pkrtz(h0, h1);
    }
}

// One LSTM step, half-step software-pipelined. On entry: acc = full gates(t),
// axw = bias + W^T x_{t+1}, XN = x_{t+2}. On exit: acc = gates(t+1),
// axw = bias + W^T x_{t+2}, XN = x_{t+4} (if DO_LOAD).
// Phase order: epi0 -> 8 U_lo MFMAs (overlap) -> epi1 -> 8 U_hi MFMAs
// (hf=0-feeding tiles first) -> 8 xW MFMAs + deep x prefetch.
template <bool DO_XW, bool DO_LOAD, int LOFF, bool DO_REC>
__device__ __forceinline__ void lstm_step(
    float4& XN, const float* xp,
    const half4v (&aUlo)[8], const half4v (&aUhi)[8],
    const half4v (&bW)[8], const float4v (&bias)[8],
    float4v (&acc)[8], float4v (&axw)[8], float (&cst)[2][4])
{
    h4Un hlo, hhi;
    epi_half<0>(acc, cst, hlo);                  // h_{t+1} units 0..15 (lane slice)

    float4v pacc[8];
    if (DO_REC) {
        #pragma unroll
        for (int tt = 0; tt < 8; tt++)
            pacc[tt] = __builtin_amdgcn_mfma_f32_16x16x16f16(
                aUlo[tt], hlo.v, axw[tt], 0, 0, 0);
    }

    epi_half<1>(acc, cst, hhi);                  // h_{t+1} units 16..31

    if (DO_REC) {
        // hf=0 consumers first so the next epi_half<0> starts after 4 MFMAs
        #pragma unroll
        for (int q = 0; q < 8; q++) {
            const int tt = (q < 4) ? 2 * q : 2 * (q - 4) + 1;  // 0,2,4,6,1,3,5,7
            acc[tt] = __builtin_amdgcn_mfma_f32_16x16x16f16(
                aUhi[tt], hhi.v, pacc[tt], 0, 0, 0);
        }
    }
    if (DO_XW) {
        half4v ax = pack4(XN);
        #pragma unroll
        for (int tt = 0; tt < 8; tt++)
            axw[tt] = __builtin_amdgcn_mfma_f32_16x16x16f16(
                bW[tt], ax, bias[tt], 0, 0, 0);
    }
    if (DO_LOAD)
        XN = *reinterpret_cast<const float4*>(xp + LOFF);
}

__global__ __launch_bounds__(64, 1) void lstm_mfma(
    const float* __restrict__ x,    // [B, T, F]
    const float* __restrict__ W,    // [F, 128]
    const float* __restrict__ U,    // [H, 128]
    const float* __restrict__ bg,   // [128]
    const float* __restrict__ W1,   // [H, 60]
    const float* __restrict__ b1,   // [60]
    const float* __restrict__ W2,   // [H, 60]
    const float* __restrict__ b2,   // [60]
    float* __restrict__ out)        // [2 * B * 60] (long || lat)
{
    const int lane = threadIdx.x;   // 64-thread block = 1 wave
    const int n16  = lane & 15;     // batch row within tile
    const int g    = lane >> 4;     // k-quad / D-row-quad
    const int b0   = blockIdx.x * ROWS;

    __shared__ __align__(16) __fp16 hbuf[ROWS * HSTRIDE];  // head pass only

    // ---- stationary A-frags: U^T split into K-halves, W^T, bias ----
    half4v  aUlo[8], aUhi[8], bW[8];
    float4v bias[8];
    #pragma unroll
    for (int tt = 0; tt < 8; tt++) {
        const float s = ((tt >> 1) == 2) ? 1.0f : -1.44269504088896340736f;
        const int colA = gcol(tt, n16);
        half4v ulo, uhi, w4;
        #pragma unroll
        for (int j = 0; j < 4; j++) {
            ulo[j] = (__fp16)(U[(4 * g + j) * GATES + colA] * s);
            uhi[j] = (__fp16)(U[(16 + 4 * g + j) * GATES + colA] * s);
            w4[j]  = (__fp16)(W[(4 * g + j) * GATES + colA] * s);
        }
        aUlo[tt] = ulo;
        aUhi[tt] = uhi;
        bW[tt]   = w4;
        float4v bv;
        #pragma unroll
        for (int r = 0; r < 4; r++)
            bv[r] = bg[gcol(tt, 4 * g + r)] * s;
        bias[tt] = bv;
    }

    // x source: lane reads x[b0+n16][t][4g .. 4g+3] (B-frag of x^T)
    const float* xrow = x + (size_t)(b0 + n16) * TSTEPS * FEAT + 4 * g;

    // acc(0) = bias + W^T x_0 (h_0 = 0); axw = bias + W^T x_1
    float4v acc[8], axw[8];
    {
        half4v a0 = pack4(*reinterpret_cast<const float4*>(xrow));
        half4v a1 = pack4(*reinterpret_cast<const float4*>(xrow + FEAT));
        #pragma unroll
        for (int tt = 0; tt < 8; tt++) {
            acc[tt] = __builtin_amdgcn_mfma_f32_16x16x16f16(
                bW[tt], a0, bias[tt], 0, 0, 0);
            axw[tt] = __builtin_amdgcn_mfma_f32_16x16x16f16(
                bW[tt], a1, bias[tt], 0, 0, 0);
        }
    }

    float4 xf0 = *reinterpret_cast<const float4*>(xrow + 2 * FEAT);    // x_2
    float4 xf1 = *reinterpret_cast<const float4*>(xrow + 3 * FEAT);    // x_3
    float cst[2][4] = {{0.f, 0.f, 0.f, 0.f}, {0.f, 0.f, 0.f, 0.f}};

    // Branch-free main loop: steps 0..195. Invariant at step t: acc=gates(t),
    // axw=bias+xW(t+1), xf0=x_{t+2}, xf1=x_{t+3}, xp=&x_t.
    const float* xp = xrow;
    for (int it = 0; it < (TSTEPS - 4) / 2; ++it) {
        lstm_step<true, true, 4 * FEAT, true>(xf0, xp, aUlo, aUhi, bW, bias,
                                              acc, axw, cst);
        lstm_step<true, true, 5 * FEAT, true>(xf1, xp, aUlo, aUhi, bW, bias,
                                              acc, axw, cst);
        xp += 2 * FEAT;
    }
    // Peeled tail: steps 196..199 (xf0=x_198, xf1=x_199)
    lstm_step<true, false, 0, true>(xf0, xp, aUlo, aUhi, bW, bias, acc, axw, cst);   // 196
    lstm_step<true, false, 0, true>(xf1, xp, aUlo, aUhi, bW, bias, acc, axw, cst);   // 197
    lstm_step<false, false, 0, true>(xf0, xp, aUlo, aUhi, bW, bias, acc, axw, cst);  // 198
    // step 199: epilogue only -> h_T
    h4Un hlo, hhi;
    epi_half<0>(acc, cst, hlo);
    epi_half<1>(acc, cst, hhi);

    // ---- stage h_T to LDS (once), then heads: out = h_T @ W1/W2 + b ----
    // lane holds h_T[row n16][units 4g+r] (lo) and [units 16+4g+r] (hi)
    *reinterpret_cast<half4v*>(&hbuf[n16 * HSTRIDE + 4 * g]) = hlo.v;
    *reinterpret_cast<half4v*>(&hbuf[n16 * HSTRIDE + 16 + 4 * g]) = hhi.v;
    __builtin_amdgcn_wave_barrier();   // in-wave DS ordering covers the reads

    for (int idx = lane; idx < ROWS * DOUT; idx += 64) {
        const int row = idx / DOUT;
        const int d   = idx - row * DOUT;
        float s1 = b1[d], s2 = b2[d];
        #pragma unroll 8
        for (int k = 0; k < HID; k++) {
            float hv = (float)hbuf[row * HSTRIDE + k];
            s1 = fmaf(hv, W1[k * DOUT + d], s1);
            s2 = fmaf(hv, W2[k * DOUT + d], s2);
        }
        out[(size_t)(b0 + row) * DOUT + d] = s1;
        out[(size_t)BATCH * DOUT + (size_t)(b0 + row) * DOUT + d] = s2;
    }
}

extern "C" void kernel_launch(void* const* d_in, const int* in_sizes, int n_in,
                              void* d_out, int out_size, void* d_ws, size_t ws_size,
                              hipStream_t stream) {
    const float* x  = (const float*)d_in[0];
    const float* W  = (const float*)d_in[1];
    const float* U  = (const float*)d_in[2];
    const float* bg = (const float*)d_in[3];
    const float* W1 = (const float*)d_in[4];
    const float* b1 = (const float*)d_in[5];
    const float* W2 = (const float*)d_in[6];
    const float* b2 = (const float*)d_in[7];
    float* out = (float*)d_out;

    dim3 grid(BATCH / ROWS);   // 512 blocks x 1 wave, fully independent
    dim3 block(64);
    lstm_mfma<<<grid, block, 0, stream>>>(x, W, U, bg, W1, b1, W2, b2, out);
}

// Round 7
// 250.884 us; speedup vs baseline: 1.1481x; 1.1481x over previous
//
#include <hip/hip_runtime.h>

// Problem constants (match reference)
#define BATCH 8192
#define TSTEPS 200
#define FEAT 16
#define HID 32
#define GATES 128   // 4*HID, Keras order: i | f | cc | o
#define DOUT 60
#define ROWS 16     // batch rows per wave (one MFMA N-tile, transposed form)
#define HSTRIDE 40  // LDS h row stride in halves (final head pass only)

typedef __fp16 half2v __attribute__((ext_vector_type(2)));
typedef __fp16 half4v __attribute__((ext_vector_type(4)));
typedef __fp16 half8v __attribute__((ext_vector_type(8)));
typedef float  float4v __attribute__((ext_vector_type(4)));

__device__ __forceinline__ half2v pkrtz(float a, float b) {
    return __builtin_amdgcn_cvt_pkrtz(a, b);
}

__device__ __forceinline__ half4v pack4(float4 v) {
    half2v lo = pkrtz(v.x, v.y);
    half2v hi = pkrtz(v.z, v.w);
    half4v r;
    r[0] = lo[0]; r[1] = lo[1]; r[2] = hi[0]; r[3] = hi[1];
    return r;
}

// Permuted gate-column map (verified rounds 2/4). Tile tt (0..7) = gate-type
// (tt>>1: i,f,cc,o) x half (tt&1). Column m -> unit 8*(m>>2)+(m&3)+4*(tt&1).
// Lane (g,n16) owns D rows m=4g+r and emits h for units 8g+r / 8g+4+r of
// batch row n16 -- exactly its own next-step B-fragment k-range 8g..8g+7.
// Recurrence is fully register-local (no LDS / cross-lane in the loop).
__device__ __forceinline__ int gcol(int tt, int m) {
    return 32 * (tt >> 1) + 8 * (m >> 2) + (m & 3) + 4 * (tt & 1);
}

union hUn { half8v v; half2v h2[4]; };

// One LSTM step (verified R4 monolithic form -- the compiler schedules this
// body better than any hand-phased variant; R6's K-split/phased version
// regressed 37%). Gates i,f,o arrive pre-scaled by -log2(e):
// sig = 1/(1 + exp2(z~)). Trans-minimized epilogue (32 trans/step):
//   c' = (c*d_i + relu(cc)*d_f) / (d_i*d_f)   [i/f rcps merged]
//   paired batch-inverse over r-neighbors for c- and o-denominators.
// DO_XW/DO_LOAD compile-time -> single basic block per step.
template <bool DO_XW, bool DO_LOAD, int LOFF>
__device__ __forceinline__ void lstm_step(
    float4& XN, const float* xp,
    const half8v (&bU)[8], const half4v (&bW)[8], const float4v (&bias)[8],
    float4v (&accx)[8], hUn& hB, float (&cst)[2][4])
{
    float4v acc[8];
    #pragma unroll
    for (int tt = 0; tt < 8; tt++)
        acc[tt] = __builtin_amdgcn_mfma_f32_16x16x32_f16(
            bU[tt], hB.v, accx[tt], 0, 0, 0);

    if (DO_XW) {
        half4v ax = pack4(XN);
        #pragma unroll
        for (int tt = 0; tt < 8; tt++)
            accx[tt] = __builtin_amdgcn_mfma_f32_16x16x16f16(
                bW[tt], ax, bias[tt], 0, 0, 0);
    }
    if (DO_LOAD)
        XN = *reinterpret_cast<const float4*>(xp + LOFF);

    // ---- phase 1: all exponentials (trans pipe back-to-back) ----
    float ei[2][4], ef[2][4], eo[2][4];
    #pragma unroll
    for (int hf = 0; hf < 2; hf++)
        #pragma unroll
        for (int r = 0; r < 4; r++) {
            ei[hf][r] = __builtin_amdgcn_exp2f(acc[0 + hf][r]);
            ef[hf][r] = __builtin_amdgcn_exp2f(acc[2 + hf][r]);
            eo[hf][r] = __builtin_amdgcn_exp2f(acc[6 + hf][r]);
        }

    // ---- phase 2: denominators + numerators (full-rate VALU) ----
    float dd[2][4], num[2][4], dov[2][4];
    #pragma unroll
    for (int hf = 0; hf < 2; hf++)
        #pragma unroll
        for (int r = 0; r < 4; r++) {
            float di = 1.0f + ei[hf][r];
            float df = 1.0f + ef[hf][r];
            dov[hf][r] = 1.0f + eo[hf][r];
            float rc = fmaxf(acc[4 + hf][r], 0.0f);
            num[hf][r] = fmaf(cst[hf][r], di, rc * df);
            dd[hf][r]  = di * df;
        }

    // ---- phase 3: paired reciprocals + state update + pack ----
    #pragma unroll
    for (int hf = 0; hf < 2; hf++)
        #pragma unroll
        for (int p = 0; p < 2; p++) {
            const int r0 = 2 * p, r1 = 2 * p + 1;
            float Q  = __builtin_amdgcn_rcpf(dd[hf][r0] * dd[hf][r1]);
            float c0 = num[hf][r0] * (dd[hf][r1] * Q);
            float c1 = num[hf][r1] * (dd[hf][r0] * Q);
            cst[hf][r0] = c0;
            cst[hf][r1] = c1;
            float Qo = __builtin_amdgcn_rcpf(dov[hf][r0] * dov[hf][r1]);
            float h0 = fmaxf(c0, 0.0f) * (dov[hf][r1] * Qo);
            float h1 = fmaxf(c1, 0.0f) * (dov[hf][r0] * Qo);
            hB.h2[2 * hf + p] = pkrtz(h0, h1);
        }
}

__global__ __launch_bounds__(64, 1) void lstm_mfma(
    const float* __restrict__ x,    // [B, T, F]
    const float* __restrict__ W,    // [F, 128]
    const float* __restrict__ U,    // [H, 128]
    const float* __restrict__ bg,   // [128]
    const float* __restrict__ W1,   // [H, 60]
    const float* __restrict__ b1,   // [60]
    const float* __restrict__ W2,   // [H, 60]
    const float* __restrict__ b2,   // [60]
    float* __restrict__ out)        // [2 * B * 60] (long || lat)
{
    const int lane = threadIdx.x;   // 64-thread block = 1 wave
    const int n16  = lane & 15;     // batch row within tile
    const int g    = lane >> 4;     // k-quad / D-row-quad
    const int b0   = blockIdx.x * ROWS;

    __shared__ __align__(16) __fp16 hbuf[ROWS * HSTRIDE];  // head pass only

    // ---- stationary A-frags: U^T (K=32), W^T (K=16), bias (per D-row) ----
    half8v  bU[8];
    half4v  bW[8];
    float4v bias[8];
    #pragma unroll
    for (int tt = 0; tt < 8; tt++) {
        const float s = ((tt >> 1) == 2) ? 1.0f : -1.44269504088896340736f;
        const int colA = gcol(tt, n16);
        half8v u8;
        #pragma unroll
        for (int j = 0; j < 8; j++)
            u8[j] = (__fp16)(U[(8 * g + j) * GATES + colA] * s);
        bU[tt] = u8;
        half4v w4;
        #pragma unroll
        for (int j = 0; j < 4; j++)
            w4[j] = (__fp16)(W[(4 * g + j) * GATES + colA] * s);
        bW[tt] = w4;
        float4v bv;
        #pragma unroll
        for (int r = 0; r < 4; r++)
            bv[r] = bg[gcol(tt, 4 * g + r)] * s;
        bias[tt] = bv;
    }

    // x source: lane reads x[b0+n16][t][4g .. 4g+3] (B-frag of x^T)
    const float* xrow = x + (size_t)(b0 + n16) * TSTEPS * FEAT + 4 * g;

    float4 xf0 = *reinterpret_cast<const float4*>(xrow + 1 * FEAT);    // x_1
    float4 xf1 = *reinterpret_cast<const float4*>(xrow + 2 * FEAT);    // x_2
    float4 xf2 = *reinterpret_cast<const float4*>(xrow + 3 * FEAT);    // x_3
    float4 xf3 = *reinterpret_cast<const float4*>(xrow + 4 * FEAT);    // x_4

    // accx(0) = bias + W^T·x_0^T
    float4v accx[8];
    {
        half4v a0 = pack4(*reinterpret_cast<const float4*>(xrow));
        #pragma unroll
        for (int tt = 0; tt < 8; tt++)
            accx[tt] = __builtin_amdgcn_mfma_f32_16x16x16f16(
                bW[tt], a0, bias[tt], 0, 0, 0);
    }

    hUn hB;
    hB.v = (half8v)(__fp16)0.f;                    // h_0 = 0
    float cst[2][4] = {{0.f, 0.f, 0.f, 0.f}, {0.f, 0.f, 0.f, 0.f}};

    // Branch-free main loop, 4-step unrolled: steps 0..191 (48 iterations).
    // Invariant at step t: accx = bias + W^T x_t (consumed this step),
    // xf0..xf3 = x_{t+1..t+4}, xp = &x_t. Loads at constant imm offsets;
    // one pointer add per 4 steps. Wider body = cross-step scheduling at
    // 3 of 4 boundaries (vs 1 of 2 at unroll-2).
    const float* xp = xrow;
    for (int it = 0; it < (TSTEPS - 8) / 4; ++it) {
        lstm_step<true, true, 5 * FEAT>(xf0, xp, bU, bW, bias, accx, hB, cst);
        lstm_step<true, true, 6 * FEAT>(xf1, xp, bU, bW, bias, accx, hB, cst);
        lstm_step<true, true, 7 * FEAT>(xf2, xp, bU, bW, bias, accx, hB, cst);
        lstm_step<true, true, 8 * FEAT>(xf3, xp, bU, bW, bias, accx, hB, cst);
        xp += 4 * FEAT;
    }
    // Peeled tail: steps 192..199. xp = &x_192; xf0..3 = x_193..x_196.
    lstm_step<true, true, 5 * FEAT>(xf0, xp, bU, bW, bias, accx, hB, cst); // 192, loads x_197
    lstm_step<true, true, 6 * FEAT>(xf1, xp, bU, bW, bias, accx, hB, cst); // 193, loads x_198
    lstm_step<true, true, 7 * FEAT>(xf2, xp, bU, bW, bias, accx, hB, cst); // 194, loads x_199
    lstm_step<true, false, 0>(xf3, xp, bU, bW, bias, accx, hB, cst);       // 195 (x_196)
    lstm_step<true, false, 0>(xf0, xp, bU, bW, bias, accx, hB, cst);       // 196 (x_197)
    lstm_step<true, false, 0>(xf1, xp, bU, bW, bias, accx, hB, cst);       // 197 (x_198)
    lstm_step<true, false, 0>(xf2, xp, bU, bW, bias, accx, hB, cst);       // 198 (x_199)
    lstm_step<false, false, 0>(xf3, xp, bU, bW, bias, accx, hB, cst);      // 199

    // ---- stage h_T to LDS (once), then heads: out = h_T @ W1/W2 + b ----
    // lane holds h_T for (row n16, units 8g..8g+7): contiguous 16B store.
    *reinterpret_cast<half8v*>(&hbuf[n16 * HSTRIDE + 8 * g]) = hB.v;
    __builtin_amdgcn_wave_barrier();   // in-wave DS ordering covers the reads

    for (int idx = lane; idx < ROWS * DOUT; idx += 64) {
        const int row = idx / DOUT;
        const int d   = idx - row * DOUT;
        float s1 = b1[d], s2 = b2[d];
        #pragma unroll 8
        for (int k = 0; k < HID; k++) {
            float hv = (float)hbuf[row * HSTRIDE + k];
            s1 = fmaf(hv, W1[k * DOUT + d], s1);
            s2 = fmaf(hv, W2[k * DOUT + d], s2);
        }
        out[(size_t)(b0 + row) * DOUT + d] = s1;
        out[(size_t)BATCH * DOUT + (size_t)(b0 + row) * DOUT + d] = s2;
    }
}

extern "C" void kernel_launch(void* const* d_in, const int* in_sizes, int n_in,
                              void* d_out, int out_size, void* d_ws, size_t ws_size,
                              hipStream_t stream) {
    const float* x  = (const float*)d_in[0];
    const float* W  = (const float*)d_in[1];
    const float* U  = (const float*)d_in[2];
    const float* bg = (const float*)d_in[3];
    const float* W1 = (const float*)d_in[4];
    const float* b1 = (const float*)d_in[5];
    const float* W2 = (const float*)d_in[6];
    const float* b2 = (const float*)d_in[7];
    float* out = (float*)d_out;

    dim3 grid(BATCH / ROWS);   // 512 blocks x 1 wave, fully independent
    dim3 block(64);
    lstm_mfma<<<grid, block, 0, stream>>>(x, W, U, bg, W1, b1, W2, b2, out);
}

// Round 8
// 238.111 us; speedup vs baseline: 1.2097x; 1.0536x over previous
//
#include <hip/hip_runtime.h>

// Problem constants (match reference)
#define BATCH 8192
#define TSTEPS 200
#define FEAT 16
#define HID 32
#define GATES 128   // 4*HID, Keras order: i | f | cc | o
#define DOUT 60
#define ROWS 16     // batch rows per wave (one MFMA N-tile, transposed form)
#define HSTRIDE 40  // LDS h row stride in halves (final head pass only)

typedef __fp16 half2v __attribute__((ext_vector_type(2)));
typedef __fp16 half4v __attribute__((ext_vector_type(4)));
typedef __fp16 half8v __attribute__((ext_vector_type(8)));
typedef float  float4v __attribute__((ext_vector_type(4)));

__device__ __forceinline__ half2v pkrtz(float a, float b) {
    return __builtin_amdgcn_cvt_pkrtz(a, b);
}

__device__ __forceinline__ half4v pack4(float4 v) {
    half2v lo = pkrtz(v.x, v.y);
    half2v hi = pkrtz(v.z, v.w);
    half4v r;
    r[0] = lo[0]; r[1] = lo[1]; r[2] = hi[0]; r[3] = hi[1];
    return r;
}

// Permuted gate-column map (verified rounds 2/4). Tile tt (0..7) = gate-type
// (tt>>1: i,f,cc,o) x half (tt&1). Column m -> unit 8*(m>>2)+(m&3)+4*(tt&1).
// Lane (g,n16) owns D rows m=4g+r and emits h for units 8g+r / 8g+4+r of
// batch row n16 -- exactly its own next-step B-fragment k-range 8g..8g+7.
// Recurrence is fully register-local (no LDS / cross-lane in the loop).
__device__ __forceinline__ int gcol(int tt, int m) {
    return 32 * (tt >> 1) + 8 * (m >> 2) + (m & 3) + 4 * (tt & 1);
}

union hUn { half8v v; half2v h2[4]; };

// One LSTM step (R4 monolithic form -- the compiler schedules this body
// better than any hand-phased variant: R6 K-split regressed 37%, R7
// unroll-4 regressed 8%). Gates i,f,o arrive pre-scaled by -log2(e):
// sig = 1/(1 + exp2(z~)). Trans-minimized epilogue, now 28 trans/step
// (24 exp2 + 4 rcp):
//   num = c*d_i + relu(cc)*d_f ;  dd = d_i*d_f ;  e = dd*d_o
//   c'  = num/dd = num*(ie*d_o) ;  h = relu(num)/(dd*d_o) = relu(num)*ie
//   where ie = 1/e via ONE rcp per element-pair: Q=rcp(e0*e1),
//   ie0=Q*e1, ie1=Q*e0.  (relu commutes with the positive division.)
// DO_XW/DO_LOAD compile-time -> single basic block per step.
template <bool DO_XW, bool DO_LOAD, int LOFF>
__device__ __forceinline__ void lstm_step(
    float4& XN, const float* xp,
    const half8v (&bU)[8], const half4v (&bW)[8], const float4v (&bias)[8],
    float4v (&accx)[8], hUn& hB, float (&cst)[2][4])
{
    float4v acc[8];
    #pragma unroll
    for (int tt = 0; tt < 8; tt++)
        acc[tt] = __builtin_amdgcn_mfma_f32_16x16x32_f16(
            bU[tt], hB.v, accx[tt], 0, 0, 0);

    if (DO_XW) {
        half4v ax = pack4(XN);
        #pragma unroll
        for (int tt = 0; tt < 8; tt++)
            accx[tt] = __builtin_amdgcn_mfma_f32_16x16x16f16(
                bW[tt], ax, bias[tt], 0, 0, 0);
    }
    if (DO_LOAD)
        XN = *reinterpret_cast<const float4*>(xp + LOFF);

    // ---- phase 1: all exponentials (trans pipe back-to-back) ----
    float ei[2][4], ef[2][4], eo[2][4];
    #pragma unroll
    for (int hf = 0; hf < 2; hf++)
        #pragma unroll
        for (int r = 0; r < 4; r++) {
            ei[hf][r] = __builtin_amdgcn_exp2f(acc[0 + hf][r]);
            ef[hf][r] = __builtin_amdgcn_exp2f(acc[2 + hf][r]);
            eo[hf][r] = __builtin_amdgcn_exp2f(acc[6 + hf][r]);
        }

    // ---- phase 2: denominators, numerators, merged e = dd*dov ----
    float ee[2][4], num[2][4], dov[2][4];
    #pragma unroll
    for (int hf = 0; hf < 2; hf++)
        #pragma unroll
        for (int r = 0; r < 4; r++) {
            float di = 1.0f + ei[hf][r];
            float df = 1.0f + ef[hf][r];
            dov[hf][r] = 1.0f + eo[hf][r];
            float rc = fmaxf(acc[4 + hf][r], 0.0f);
            num[hf][r] = fmaf(cst[hf][r], di, rc * df);
            float dd = di * df;
            ee[hf][r]  = dd * dov[hf][r];
        }

    // ---- phase 3: ONE rcp per pair + state update + pack ----
    #pragma unroll
    for (int hf = 0; hf < 2; hf++)
        #pragma unroll
        for (int p = 0; p < 2; p++) {
            const int r0 = 2 * p, r1 = 2 * p + 1;
            float Q   = __builtin_amdgcn_rcpf(ee[hf][r0] * ee[hf][r1]);
            float ie0 = Q * ee[hf][r1];           // 1/(dd0*dov0)
            float ie1 = Q * ee[hf][r0];           // 1/(dd1*dov1)
            float c0  = num[hf][r0] * (ie0 * dov[hf][r0]);   // num0/dd0
            float c1  = num[hf][r1] * (ie1 * dov[hf][r1]);
            cst[hf][r0] = c0;
            cst[hf][r1] = c1;
            float h0  = fmaxf(num[hf][r0], 0.0f) * ie0;      // relu(c0)*sig(o0)
            float h1  = fmaxf(num[hf][r1], 0.0f) * ie1;
            hB.h2[2 * hf + p] = pkrtz(h0, h1);
        }
}

__global__ __launch_bounds__(64, 1) void lstm_mfma(
    const float* __restrict__ x,    // [B, T, F]
    const float* __restrict__ W,    // [F, 128]
    const float* __restrict__ U,    // [H, 128]
    const float* __restrict__ bg,   // [128]
    const float* __restrict__ W1,   // [H, 60]
    const float* __restrict__ b1,   // [60]
    const float* __restrict__ W2,   // [H, 60]
    const float* __restrict__ b2,   // [60]
    float* __restrict__ out)        // [2 * B * 60] (long || lat)
{
    const int lane = threadIdx.x;   // 64-thread block = 1 wave
    const int n16  = lane & 15;     // batch row within tile
    const int g    = lane >> 4;     // k-quad / D-row-quad
    const int b0   = blockIdx.x * ROWS;

    __shared__ __align__(16) __fp16 hbuf[ROWS * HSTRIDE];  // head pass only

    // ---- stationary A-frags: U^T (K=32), W^T (K=16), bias (per D-row) ----
    half8v  bU[8];
    half4v  bW[8];
    float4v bias[8];
    #pragma unroll
    for (int tt = 0; tt < 8; tt++) {
        const float s = ((tt >> 1) == 2) ? 1.0f : -1.44269504088896340736f;
        const int colA = gcol(tt, n16);
        half8v u8;
        #pragma unroll
        for (int j = 0; j < 8; j++)
            u8[j] = (__fp16)(U[(8 * g + j) * GATES + colA] * s);
        bU[tt] = u8;
        half4v w4;
        #pragma unroll
        for (int j = 0; j < 4; j++)
            w4[j] = (__fp16)(W[(4 * g + j) * GATES + colA] * s);
        bW[tt] = w4;
        float4v bv;
        #pragma unroll
        for (int r = 0; r < 4; r++)
            bv[r] = bg[gcol(tt, 4 * g + r)] * s;
        bias[tt] = bv;
    }

    // x source: lane reads x[b0+n16][t][4g .. 4g+3] (B-frag of x^T)
    const float* xrow = x + (size_t)(b0 + n16) * TSTEPS * FEAT + 4 * g;

    float4 xf0 = *reinterpret_cast<const float4*>(xrow + FEAT);        // x_1
    float4 xf1 = *reinterpret_cast<const float4*>(xrow + 2 * FEAT);    // x_2

    // accx(0) = bias + W^T·x_0^T
    float4v accx[8];
    {
        half4v a0 = pack4(*reinterpret_cast<const float4*>(xrow));
        #pragma unroll
        for (int tt = 0; tt < 8; tt++)
            accx[tt] = __builtin_amdgcn_mfma_f32_16x16x16f16(
                bW[tt], a0, bias[tt], 0, 0, 0);
    }

    hUn hB;
    hB.v = (half8v)(__fp16)0.f;                    // h_0 = 0
    float cst[2][4] = {{0.f, 0.f, 0.f, 0.f}, {0.f, 0.f, 0.f, 0.f}};

    // Branch-free main loop: steps 0..195 (98 two-step iterations).
    // Invariant at iteration start (step t): xf0 = x_{t+1}, xf1 = x_{t+2},
    // accx = bias + W^T x_t, xp = &x_t. Loads hit constant imm offsets.
    // (2-step unroll verified best: unroll-4 regressed via register
    // pressure, R7.)
    const float* xp = xrow;
    for (int it = 0; it < (TSTEPS - 4) / 2; ++it) {
        lstm_step<true, true, 3 * FEAT>(xf0, xp, bU, bW, bias, accx, hB, cst);
        lstm_step<true, true, 4 * FEAT>(xf1, xp, bU, bW, bias, accx, hB, cst);
        xp += 2 * FEAT;
    }
    // Peeled tail: steps 196..199 (xp == &x_196; xf0=x_197, xf1=x_198)
    lstm_step<true, true, 3 * FEAT>(xf0, xp, bU, bW, bias, accx, hB, cst); // 196, loads x_199
    lstm_step<true, false, 0>(xf1, xp, bU, bW, bias, accx, hB, cst);       // 197
    lstm_step<true, false, 0>(xf0, xp, bU, bW, bias, accx, hB, cst);       // 198 (xf0 = x_199)
    lstm_step<false, false, 0>(xf1, xp, bU, bW, bias, accx, hB, cst);      // 199

    // ---- stage h_T to LDS (once), then heads: out = h_T @ W1/W2 + b ----
    // lane holds h_T for (row n16, units 8g..8g+7): contiguous 16B store.
    *reinterpret_cast<half8v*>(&hbuf[n16 * HSTRIDE + 8 * g]) = hB.v;
    __builtin_amdgcn_wave_barrier();   // in-wave DS ordering covers the reads

    for (int idx = lane; idx < ROWS * DOUT; idx += 64) {
        const int row = idx / DOUT;
        const int d   = idx - row * DOUT;
        float s1 = b1[d], s2 = b2[d];
        #pragma unroll 8
        for (int k = 0; k < HID; k++) {
            float hv = (float)hbuf[row * HSTRIDE + k];
            s1 = fmaf(hv, W1[k * DOUT + d], s1);
            s2 = fmaf(hv, W2[k * DOUT + d], s2);
        }
        out[(size_t)(b0 + row) * DOUT + d] = s1;
        out[(size_t)BATCH * DOUT + (size_t)(b0 + row) * DOUT + d] = s2;
    }
}

extern "C" void kernel_launch(void* const* d_in, const int* in_sizes, int n_in,
                              void* d_out, int out_size, void* d_ws, size_t ws_size,
                              hipStream_t stream) {
    const float* x  = (const float*)d_in[0];
    const float* W  = (const float*)d_in[1];
    const float* U  = (const float*)d_in[2];
    const float* bg = (const float*)d_in[3];
    const float* W1 = (const float*)d_in[4];
    const float* b1 = (const float*)d_in[5];
    const float* W2 = (const float*)d_in[6];
    const float* b2 = (const float*)d_in[7];
    float* out = (float*)d_out;

    dim3 grid(BATCH / ROWS);   // 512 blocks x 1 wave, fully independent
    dim3 block(64);
    lstm_mfma<<<grid, block, 0, stream>>>(x, W, U, bg, W1, b1, W2, b2, out);
}

// Round 9
// 232.588 us; speedup vs baseline: 1.2385x; 1.0237x over previous
//
#include <hip/hip_runtime.h>

// Problem constants (match reference)
#define BATCH 8192
#define TSTEPS 200
#define FEAT 16
#define HID 32
#define GATES 128   // 4*HID, Keras order: i | f | cc | o
#define DOUT 60
#define ROWS 16     // batch rows per wave (one MFMA N-tile, transposed form)
#define HSTRIDE 40  // LDS h row stride in halves (final head pass only)

typedef __fp16 half2v __attribute__((ext_vector_type(2)));
typedef __fp16 half4v __attribute__((ext_vector_type(4)));
typedef __fp16 half8v __attribute__((ext_vector_type(8)));
typedef float  float2v __attribute__((ext_vector_type(2)));
typedef float  float4v __attribute__((ext_vector_type(4)));

__device__ __forceinline__ half2v pkrtz(float a, float b) {
    return __builtin_amdgcn_cvt_pkrtz(a, b);
}

__device__ __forceinline__ half4v pack4(float4 v) {
    half2v lo = pkrtz(v.x, v.y);
    half2v hi = pkrtz(v.z, v.w);
    half4v r;
    r[0] = lo[0]; r[1] = lo[1]; r[2] = hi[0]; r[3] = hi[1];
    return r;
}

// Permuted gate-column map (verified rounds 2/4). Tile tt (0..7) = gate-type
// (tt>>1: i,f,cc,o) x half (tt&1). Column m -> unit 8*(m>>2)+(m&3)+4*(tt&1).
// Lane (g,n16) owns D rows m=4g+r and emits h for units 8g+r / 8g+4+r of
// batch row n16 -- exactly its own next-step B-fragment k-range 8g..8g+7.
// Recurrence is fully register-local (no LDS / cross-lane in the loop).
__device__ __forceinline__ int gcol(int tt, int m) {
    return 32 * (tt >> 1) + 8 * (m >> 2) + (m & 3) + 4 * (tt & 1);
}

union hUn { half8v v; half2v h2[4]; };

// One LSTM step (R4 monolithic form -- the compiler schedules this body
// better than any hand-phased variant: R6 K-split regressed 37%, R7
// unroll-4 regressed 8%). Gates i,f,o arrive pre-scaled by -log2(e):
// sig = 1/(1 + exp2(z~)). Trans-minimized epilogue (24 exp2 + 4 rcp):
//   num = c*d_i + relu(cc)*d_f ;  ee = d_i*d_f*d_o
//   c'  = num*(ie*d_o) ;  h = relu(num)*ie ;  ie = 1/ee via one rcp/pair.
// R9: phases 2-3 on float2 vectors so the backend can emit packed-f32
// VALU (v_pk_add/mul/fma_f32, 2 f32/lane/op) -- per-element math is
// IEEE-identical to R8 (bit-exact absmax), only issue count changes.
// DO_XW/DO_LOAD compile-time -> single basic block per step.
template <bool DO_XW, bool DO_LOAD, int LOFF>
__device__ __forceinline__ void lstm_step(
    float4& XN, const float* xp,
    const half8v (&bU)[8], const half4v (&bW)[8], const float4v (&bias)[8],
    float4v (&accx)[8], hUn& hB, float2v (&cst)[2][2])
{
    float4v acc[8];
    #pragma unroll
    for (int tt = 0; tt < 8; tt++)
        acc[tt] = __builtin_amdgcn_mfma_f32_16x16x32_f16(
            bU[tt], hB.v, accx[tt], 0, 0, 0);

    if (DO_XW) {
        half4v ax = pack4(XN);
        #pragma unroll
        for (int tt = 0; tt < 8; tt++)
            accx[tt] = __builtin_amdgcn_mfma_f32_16x16x16f16(
                bW[tt], ax, bias[tt], 0, 0, 0);
    }
    if (DO_LOAD)
        XN = *reinterpret_cast<const float4*>(xp + LOFF);

    // ---- phase 1: all exponentials (trans pipe, scalar per element) ----
    float2v ei[2][2], ef[2][2], eo[2][2];
    #pragma unroll
    for (int hf = 0; hf < 2; hf++)
        #pragma unroll
        for (int p = 0; p < 2; p++) {
            ei[hf][p][0] = __builtin_amdgcn_exp2f(acc[0 + hf][2 * p]);
            ei[hf][p][1] = __builtin_amdgcn_exp2f(acc[0 + hf][2 * p + 1]);
            ef[hf][p][0] = __builtin_amdgcn_exp2f(acc[2 + hf][2 * p]);
            ef[hf][p][1] = __builtin_amdgcn_exp2f(acc[2 + hf][2 * p + 1]);
            eo[hf][p][0] = __builtin_amdgcn_exp2f(acc[6 + hf][2 * p]);
            eo[hf][p][1] = __builtin_amdgcn_exp2f(acc[6 + hf][2 * p + 1]);
        }

    // ---- phases 2+3: packed-f32 pairwise math + one rcp per pair ----
    const float2v one  = {1.0f, 1.0f};
    const float2v zero = {0.0f, 0.0f};
    #pragma unroll
    for (int hf = 0; hf < 2; hf++)
        #pragma unroll
        for (int p = 0; p < 2; p++) {
            float2v di  = one + ei[hf][p];
            float2v df  = one + ef[hf][p];
            float2v dov = one + eo[hf][p];
            float2v cc2 = {acc[4 + hf][2 * p], acc[4 + hf][2 * p + 1]};
            float2v rc  = __builtin_elementwise_max(cc2, zero);
            float2v num = __builtin_elementwise_fma(cst[hf][p], di, rc * df);
            float2v ee  = (di * df) * dov;
            float   Q   = __builtin_amdgcn_rcpf(ee[0] * ee[1]);
            float2v ie  = {Q * ee[1], Q * ee[0]};        // 1/(dd*dov) per elem
            float2v c2  = num * (ie * dov);              // num/dd
            cst[hf][p]  = c2;
            float2v h2  = __builtin_elementwise_max(num, zero) * ie;
            hB.h2[2 * hf + p] = pkrtz(h2[0], h2[1]);
        }
}

__global__ __launch_bounds__(64, 1) void lstm_mfma(
    const float* __restrict__ x,    // [B, T, F]
    const float* __restrict__ W,    // [F, 128]
    const float* __restrict__ U,    // [H, 128]
    const float* __restrict__ bg,   // [128]
    const float* __restrict__ W1,   // [H, 60]
    const float* __restrict__ b1,   // [60]
    const float* __restrict__ W2,   // [H, 60]
    const float* __restrict__ b2,   // [60]
    float* __restrict__ out)        // [2 * B * 60] (long || lat)
{
    const int lane = threadIdx.x;   // 64-thread block = 1 wave
    const int n16  = lane & 15;     // batch row within tile
    const int g    = lane >> 4;     // k-quad / D-row-quad
    const int b0   = blockIdx.x * ROWS;

    __shared__ __align__(16) __fp16 hbuf[ROWS * HSTRIDE];  // head pass only

    // ---- stationary A-frags: U^T (K=32), W^T (K=16), bias (per D-row) ----
    half8v  bU[8];
    half4v  bW[8];
    float4v bias[8];
    #pragma unroll
    for (int tt = 0; tt < 8; tt++) {
        const float s = ((tt >> 1) == 2) ? 1.0f : -1.44269504088896340736f;
        const int colA = gcol(tt, n16);
        half8v u8;
        #pragma unroll
        for (int j = 0; j < 8; j++)
            u8[j] = (__fp16)(U[(8 * g + j) * GATES + colA] * s);
        bU[tt] = u8;
        half4v w4;
        #pragma unroll
        for (int j = 0; j < 4; j++)
            w4[j] = (__fp16)(W[(4 * g + j) * GATES + colA] * s);
        bW[tt] = w4;
        float4v bv;
        #pragma unroll
        for (int r = 0; r < 4; r++)
            bv[r] = bg[gcol(tt, 4 * g + r)] * s;
        bias[tt] = bv;
    }

    // x source: lane reads x[b0+n16][t][4g .. 4g+3] (B-frag of x^T)
    const float* xrow = x + (size_t)(b0 + n16) * TSTEPS * FEAT + 4 * g;

    float4 xf0 = *reinterpret_cast<const float4*>(xrow + FEAT);        // x_1
    float4 xf1 = *reinterpret_cast<const float4*>(xrow + 2 * FEAT);    // x_2

    // accx(0) = bias + W^T·x_0^T
    float4v accx[8];
    {
        half4v a0 = pack4(*reinterpret_cast<const float4*>(xrow));
        #pragma unroll
        for (int tt = 0; tt < 8; tt++)
            accx[tt] = __builtin_amdgcn_mfma_f32_16x16x16f16(
                bW[tt], a0, bias[tt], 0, 0, 0);
    }

    hUn hB;
    hB.v = (half8v)(__fp16)0.f;                    // h_0 = 0
    float2v cst[2][2] = {{{0.f, 0.f}, {0.f, 0.f}}, {{0.f, 0.f}, {0.f, 0.f}}};

    // Branch-free main loop: steps 0..195 (98 two-step iterations).
    // Invariant at iteration start (step t): xf0 = x_{t+1}, xf1 = x_{t+2},
    // accx = bias + W^T x_t, xp = &x_t. Loads hit constant imm offsets.
    // (2-step unroll verified best: unroll-4 regressed via register
    // pressure, R7.)
    const float* xp = xrow;
    for (int it = 0; it < (TSTEPS - 4) / 2; ++it) {
        lstm_step<true, true, 3 * FEAT>(xf0, xp, bU, bW, bias, accx, hB, cst);
        lstm_step<true, true, 4 * FEAT>(xf1, xp, bU, bW, bias, accx, hB, cst);
        xp += 2 * FEAT;
    }
    // Peeled tail: steps 196..199 (xp == &x_196; xf0=x_197, xf1=x_198)
    lstm_step<true, true, 3 * FEAT>(xf0, xp, bU, bW, bias, accx, hB, cst); // 196, loads x_199
    lstm_step<true, false, 0>(xf1, xp, bU, bW, bias, accx, hB, cst);       // 197
    lstm_step<true, false, 0>(xf0, xp, bU, bW, bias, accx, hB, cst);       // 198 (xf0 = x_199)
    lstm_step<false, false, 0>(xf1, xp, bU, bW, bias, accx, hB, cst);      // 199

    // ---- stage h_T to LDS (once), then heads: out = h_T @ W1/W2 + b ----
    // lane holds h_T for (row n16, units 8g..8g+7): contiguous 16B store.
    *reinterpret_cast<half8v*>(&hbuf[n16 * HSTRIDE + 8 * g]) = hB.v;
    __builtin_amdgcn_wave_barrier();   // in-wave DS ordering covers the reads

    for (int idx = lane; idx < ROWS * DOUT; idx += 64) {
        const int row = idx / DOUT;
        const int d   = idx - row * DOUT;
        float s1 = b1[d], s2 = b2[d];
        #pragma unroll 8
        for (int k = 0; k < HID; k++) {
            float hv = (float)hbuf[row * HSTRIDE + k];
            s1 = fmaf(hv, W1[k * DOUT + d], s1);
            s2 = fmaf(hv, W2[k * DOUT + d], s2);
        }
        out[(size_t)(b0 + row) * DOUT + d] = s1;
        out[(size_t)BATCH * DOUT + (size_t)(b0 + row) * DOUT + d] = s2;
    }
}

extern "C" void kernel_launch(void* const* d_in, const int* in_sizes, int n_in,
                              void* d_out, int out_size, void* d_ws, size_t ws_size,
                              hipStream_t stream) {
    const float* x  = (const float*)d_in[0];
    const float* W  = (const float*)d_in[1];
    const float* U  = (const float*)d_in[2];
    const float* bg = (const float*)d_in[3];
    const float* W1 = (const float*)d_in[4];
    const float* b1 = (const float*)d_in[5];
    const float* W2 = (const float*)d_in[6];
    const float* b2 = (const float*)d_in[7];
    float* out = (float*)d_out;

    dim3 grid(BATCH / ROWS);   // 512 blocks x 1 wave, fully independent
    dim3 block(64);
    lstm_mfma<<<grid, block, 0, stream>>>(x, W, U, bg, W1, b1, W2, b2, out);
}